// Round 2
// baseline (247.573 us; speedup 1.0000x reference)
//
#include <hip/hip_runtime.h>
#include <hip/hip_bf16.h>

typedef short short8 __attribute__((ext_vector_type(8)));
typedef float f32x4  __attribute__((ext_vector_type(4)));
typedef unsigned int u32x4 __attribute__((ext_vector_type(4)));
typedef unsigned int u32x2 __attribute__((ext_vector_type(2)));

// Problem constants: B=4, C=64, D=32, H=64, W=64, K=32
#define BB      4
#define CC      64
#define KK      32
#define NN      131072
#define TILE    128      // n per block-iteration (32 per wave)
#define NTILE   1024     // NN/TILE
#define JBLK    192      // blocks per batch image (768 total = 3/CU)
#define THREADS 256
#define PSZ     2080     // per-block partial: K*C + K

// per-wave LDS strides (bf16 elements); rows 16B-aligned
#define XN_S 72          // 144 B
#define XC_S 40          // 80 B
#define AK_S 40          // 80 B

struct Tiles {
    unsigned short Xn[4][32][XN_S];   // [wave][n][c]
    unsigned short Xc[4][64][XC_S];   // [wave][c][n]
    unsigned short Ak[4][32][AK_S];   // [wave][k][n]
};
union SMem {
    Tiles t;                          // 49152 B
    float red[4][2048];               // epilogue cross-wave reduce (32768 B)
};

// within-wave LDS write->read ordering: DS pipe is in-order per wave.
// Drain lgkm; sched_barrier(0) blocks ANY compiler motion across this point
// (rule #18: "memory" clobber alone does not pin register-only MFMA).
__device__ __forceinline__ void wave_sync() {
    asm volatile("s_waitcnt lgkmcnt(0)" ::: "memory");
    __builtin_amdgcn_sched_barrier(0);
}

__device__ __forceinline__ unsigned pk2(float a, float b) {
    union { __hip_bfloat162 h; unsigned u; } cv;
    cv.h = __float22bfloat162_rn(make_float2(a, b));
    return cv.u;
}
__device__ __forceinline__ unsigned short b16(float a) {
    union { __hip_bfloat16 h; unsigned short u; } cv;
    cv.h = __float2bfloat16(a);
    return cv.u;
}

__global__ __launch_bounds__(THREADS, 3) void main_kernel(
        const float* __restrict__ X,
        const float* __restrict__ cw,
        const float* __restrict__ scale,
        float* __restrict__ out,      // coefA at offset 8192
        float* __restrict__ ws) {
    __shared__ __align__(16) SMem sm;
    __shared__ float asml[4][KK];

    const int tid  = threadIdx.x;
    const int b    = blockIdx.x / JBLK;
    const int j    = blockIdx.x % JBLK;
    const int lane = tid & 63;
    const int w    = tid >> 6;        // wave 0..3
    const int q    = lane >> 4;       // quad
    const int l15  = lane & 15;
    const int nq   = lane & 7;        // n-quad within the wave's 32-n tile
    const int co   = lane >> 3;       // c-octet (8 c's per lane)

    const float* Xb   = X + (size_t)b * CC * NN;
    float*       outA = out + 8192 + (size_t)b * KK * NN;

    unsigned short (*Xn)[XN_S] = sm.t.Xn[w];
    unsigned short (*Xc)[XC_S] = sm.t.Xc[w];
    unsigned short (*Ak)[AK_S] = sm.t.Ak[w];

    // ---- prologue: cw fragments + per-lane k-constants (fused precompute) ----
    short8 cwf[2][2];
    float c2acc[2] = {0.f, 0.f};
    #pragma unroll
    for (int kt = 0; kt < 2; ++kt)
        #pragma unroll
        for (int s = 0; s < 2; ++s) {
            const float* cp = cw + (16 * kt + l15) * CC + 32 * s + 8 * q;
            #pragma unroll
            for (int jj = 0; jj < 8; ++jj) {
                float v = cp[jj];
                c2acc[kt] += v * v;
                cwf[kt][s][jj] = (short)b16(v);
            }
        }
    #pragma unroll
    for (int kt = 0; kt < 2; ++kt) {   // reduce partial |c|^2 over q
        c2acc[kt] += __shfl_xor(c2acc[kt], 16);
        c2acc[kt] += __shfl_xor(c2acc[kt], 32);
    }
    float s2v[2][4], sc2v[2][4], sclv[2][4];
    #pragma unroll
    for (int t2 = 0; t2 < 2; ++t2)
        #pragma unroll
        for (int r = 0; r < 4; ++r) {
            int k = 16 * t2 + 4 * q + r;
            float sk  = scale[k];
            float c2k = __shfl(c2acc[t2], 4 * q + r);
            sclv[t2][r] = sk;
            s2v[t2][r]  = -2.0f * sk;
            sc2v[t2][r] = sk * c2k;
        }

    const f32x4 zf = {0.f, 0.f, 0.f, 0.f};
    f32x4 acc2[2][4];
    #pragma unroll
    for (int kt = 0; kt < 2; ++kt)
        #pragma unroll
        for (int ct = 0; ct < 4; ++ct) acc2[kt][ct] = zf;
    float asum[2][4];
    #pragma unroll
    for (int t2 = 0; t2 < 2; ++t2)
        #pragma unroll
        for (int r = 0; r < 4; ++r) asum[t2][r] = 0.f;

    // ===== barrier-free main loop: each wave owns 32 n autonomously =====
    for (int t = j; t < NTILE; t += JBLK) {
        const size_t n0 = (size_t)t * TILE + 32 * w;   // wave's global n-offset

        // ---- load wave tile: 8 x float4 (128 B line-chunks per c-row) ----
        const float* pb = Xb + (size_t)(8 * co) * NN + n0 + 4 * nq;
        f32x4 xv[8];
        #pragma unroll
        for (int i = 0; i < 8; ++i)
            xv[i] = *(const f32x4*)(pb + (size_t)i * NN);

        // ---- stage: x2 partials + packed Xn[n][c], Xc[c][n] ----
        float xp[4] = {0.f, 0.f, 0.f, 0.f};
        #pragma unroll
        for (int i = 0; i < 8; ++i) {
            xp[0] = fmaf(xv[i][0], xv[i][0], xp[0]);
            xp[1] = fmaf(xv[i][1], xv[i][1], xp[1]);
            xp[2] = fmaf(xv[i][2], xv[i][2], xp[2]);
            xp[3] = fmaf(xv[i][3], xv[i][3], xp[3]);
        }
        #pragma unroll
        for (int dn = 0; dn < 4; ++dn) {
            u32x4 u;
            u[0] = pk2(xv[0][dn], xv[1][dn]);
            u[1] = pk2(xv[2][dn], xv[3][dn]);
            u[2] = pk2(xv[4][dn], xv[5][dn]);
            u[3] = pk2(xv[6][dn], xv[7][dn]);
            *(u32x4*)&Xn[4 * nq + dn][8 * co] = u;
        }
        #pragma unroll
        for (int i = 0; i < 8; ++i) {
            u32x2 u;
            u[0] = pk2(xv[i][0], xv[i][1]);
            u[1] = pk2(xv[i][2], xv[i][3]);
            *(u32x2*)&Xc[8 * co + i][4 * nq] = u;
        }
        // x2 totals: reduce over the 8 c-octet lanes (bits 3,4,5)
        #pragma unroll
        for (int d = 0; d < 4; ++d) {
            xp[d] += __shfl_xor(xp[d], 8);
            xp[d] += __shfl_xor(xp[d], 16);
            xp[d] += __shfl_xor(xp[d], 32);
        }

        wave_sync();   // Xn/Xc writes visible to own wave

        // ---- GEMM1: L(32k x 32n) = cw . X^T, softmax over k ----
        #pragma unroll
        for (int nt = 0; nt < 2; ++nt) {
            const int nl  = nt * 16 + l15;
            // gather x2 for column nl: owner lane = nl>>2, component = nl&3
            const int src = 4 * nt + (l15 >> 2);
            float xs0 = __shfl(xp[0], src);
            float xs1 = __shfl(xp[1], src);
            float xs2 = __shfl(xp[2], src);
            float xs3 = __shfl(xp[3], src);
            float xa  = (l15 & 1) ? xs1 : xs0;
            float xb2 = (l15 & 1) ? xs3 : xs2;
            float x2n = (l15 & 2) ? xb2 : xa;

            short8 bx0 = *(const short8*)&Xn[nl][8 * q];
            short8 bx1 = *(const short8*)&Xn[nl][32 + 8 * q];
            f32x4 lt[2];
            lt[0] = __builtin_amdgcn_mfma_f32_16x16x32_bf16(cwf[0][0], bx0, zf, 0, 0, 0);
            lt[0] = __builtin_amdgcn_mfma_f32_16x16x32_bf16(cwf[0][1], bx1, lt[0], 0, 0, 0);
            lt[1] = __builtin_amdgcn_mfma_f32_16x16x32_bf16(cwf[1][0], bx0, zf, 0, 0, 0);
            lt[1] = __builtin_amdgcn_mfma_f32_16x16x32_bf16(cwf[1][1], bx1, lt[1], 0, 0, 0);

            float av[2][4];
            float m = -3.0e38f;
            #pragma unroll
            for (int t2 = 0; t2 < 2; ++t2)
                #pragma unroll
                for (int r = 0; r < 4; ++r) {
                    float L = fmaf(s2v[t2][r], lt[t2][r],
                                   fmaf(sclv[t2][r], x2n, sc2v[t2][r]));
                    av[t2][r] = L;
                    m = fmaxf(m, L);
                }
            m = fmaxf(m, __shfl_xor(m, 16));
            m = fmaxf(m, __shfl_xor(m, 32));
            float s = 0.f;
            #pragma unroll
            for (int t2 = 0; t2 < 2; ++t2)
                #pragma unroll
                for (int r = 0; r < 4; ++r) {
                    float e = __expf(av[t2][r] - m);
                    av[t2][r] = e;
                    s += e;
                }
            s += __shfl_xor(s, 16);
            s += __shfl_xor(s, 32);
            const float inv = 1.0f / s;
            #pragma unroll
            for (int t2 = 0; t2 < 2; ++t2)
                #pragma unroll
                for (int r = 0; r < 4; ++r) {
                    float a = av[t2][r] * inv;
                    int k = 16 * t2 + 4 * q + r;
                    asum[t2][r] += a;
                    outA[(size_t)k * NN + n0 + nl] = a;   // store, never drained in-loop
                    Ak[k][nl] = b16(a);
                }
        }

        wave_sync();   // Ak writes visible

        // ---- GEMM2: acc2(32k x 64c) += A(32k x 32n) . X(32n x 64c) ----
        short8 af0 = *(const short8*)&Ak[l15][8 * q];
        short8 af1 = *(const short8*)&Ak[16 + l15][8 * q];
        #pragma unroll
        for (int ct = 0; ct < 4; ++ct) {
            short8 bc = *(const short8*)&Xc[16 * ct + l15][8 * q];
            acc2[0][ct] = __builtin_amdgcn_mfma_f32_16x16x32_bf16(af0, bc, acc2[0][ct], 0, 0, 0);
            acc2[1][ct] = __builtin_amdgcn_mfma_f32_16x16x32_bf16(af1, bc, acc2[1][ct], 0, 0, 0);
        }
        // pin GEMM2's ds_reads ahead of next iteration's staging ds_writes
        __builtin_amdgcn_sched_barrier(0);
    }

    // ---- epilogue: cross-wave reduce, per-block partials to ws (no atomics) ----
    __syncthreads();   // all waves done with their LDS tiles; reuse as red[]
    #pragma unroll
    for (int kt = 0; kt < 2; ++kt)
        #pragma unroll
        for (int ct = 0; ct < 4; ++ct)
            #pragma unroll
            for (int r = 0; r < 4; ++r) {
                int k = 16 * kt + 4 * q + r;
                int c = 16 * ct + l15;
                sm.red[w][k * CC + c] = acc2[kt][ct][r];
            }
    #pragma unroll
    for (int t2 = 0; t2 < 2; ++t2)
        #pragma unroll
        for (int r = 0; r < 4; ++r) {
            float v = asum[t2][r];
            v += __shfl_xor(v, 1); v += __shfl_xor(v, 2);
            v += __shfl_xor(v, 4); v += __shfl_xor(v, 8);
            if (l15 == 0) asml[w][16 * t2 + 4 * q + r] = v;
        }
    __syncthreads();
    float* p = ws + (size_t)blockIdx.x * PSZ;
    #pragma unroll
    for (int i = 0; i < 8; ++i) {
        int idx = tid + 256 * i;
        p[idx] = sm.red[0][idx] + sm.red[1][idx] + sm.red[2][idx] + sm.red[3][idx];
    }
    if (tid < KK)
        p[2048 + tid] = asml[0][tid] + asml[1][tid] + asml[2][tid] + asml[3][tid];
}

__global__ __launch_bounds__(256) void finalize_kernel(
        const float* __restrict__ cw,
        float* __restrict__ out,
        const float* __restrict__ ws) {
    __shared__ float red[4][64];
    __shared__ float ar[192];
    const int b = blockIdx.x >> 5;
    const int k = blockIdx.x & 31;
    const int c  = threadIdx.x & 63;
    const int jg = threadIdx.x >> 6;

    const float* p0 = ws + (size_t)b * JBLK * PSZ;
    float atx = 0.f;
    for (int j2 = jg; j2 < JBLK; j2 += 4)
        atx += p0[(size_t)j2 * PSZ + k * CC + c];     // coalesced
    red[jg][c] = atx;
    if (threadIdx.x < 192)
        ar[threadIdx.x] = p0[(size_t)threadIdx.x * PSZ + 2048 + k];
    __syncthreads();
    if (threadIdx.x < 64) {
        float a = red[0][c] + red[1][c] + red[2][c] + red[3][c];
        float s = ar[c] + ar[c + 64] + ar[c + 128];
        s += __shfl_xor(s, 1);  s += __shfl_xor(s, 2);  s += __shfl_xor(s, 4);
        s += __shfl_xor(s, 8);  s += __shfl_xor(s, 16); s += __shfl_xor(s, 32);
        out[(size_t)(b * KK + k) * CC + c] = a - s * cw[k * CC + c];
    }
}

extern "C" void kernel_launch(void* const* d_in, const int* in_sizes, int n_in,
                              void* d_out, int out_size, void* d_ws, size_t ws_size,
                              hipStream_t stream) {
    const float* X  = (const float*)d_in[0];
    const float* cw = (const float*)d_in[1];
    const float* sc = (const float*)d_in[2];
    float* out = (float*)d_out;
    float* ws  = (float*)d_ws;

    main_kernel<<<BB * JBLK, THREADS, 0, stream>>>(X, cw, sc, out, ws);
    finalize_kernel<<<BB * KK, 256, 0, stream>>>(cw, out, ws);
}